// Round 7
// baseline (2294.154 us; speedup 1.0000x reference)
//
#include <hip/hip_runtime.h>

#define NPTS   16384
#define RPB    256      // rows per block (4 waves x 64)
#define CPB    512      // cols per block
#define NRB    (NPTS / RPB)   // 64
#define NCB    (NPTS / CPB)   // 32

typedef short  bf16x8 __attribute__((ext_vector_type(8)));
typedef float  f32x16 __attribute__((ext_vector_type(16)));

// ---- bf16 split helpers (RNE) ----
__device__ __forceinline__ unsigned rne_bf16(float f) {
    unsigned u = __float_as_uint(f);
    return (u + 0x7fffu + ((u >> 16) & 1u)) >> 16;
}
__device__ __forceinline__ float bf16_dec(unsigned h) {
    return __uint_as_float(h << 16);
}
#define ONE_BF 0x3f80u

// K=16 slot map (A = weighted pred, B = plain tgt):
//  k0-3: ah*bh  k4-7: al*bh  k8-11: ah*bl  k12-13: 1*Tnh,1*Tnl  k14-15: Pnh*1,Pnl*1
// => acc = hi-precision dot + Tn_j + Pn_i = combined(i,j) directly.
// combined() is symmetric in (pred,tgt) => M^T is the other direction's matrix:
// row-mins of M = min_p2g, col-mins of M = min_g2p. ONE pass serves both.
// Record layout per point: 2 x bf16x8 (lane<32 reads rec[0], lane>=32 rec[1]).

__global__ __launch_bounds__(256) void prep_kernel(
    const float4* __restrict__ pred, const float4* __restrict__ tgt,
    uint4* __restrict__ wpred, uint4* __restrict__ ptgt,
    unsigned int* __restrict__ minbuf)
{
    int i = blockIdx.x * 256 + threadIdx.x;
    if (i >= NPTS) return;

    // init min buffers (replaces hipMemsetAsync dispatch)
    minbuf[i]        = 0x7f7f7f7fu;   // 3.39e38f
    minbuf[i + NPTS] = 0x7f7f7f7fu;

    unsigned onepk = ONE_BF | (ONE_BF << 16);

    {   // weighted pred record (row side)
        float4 v = pred[i];
        float n = fmaf(v.x, v.x, fmaf(v.y, v.y, fmaf(v.z, v.z, 0.5f * v.w * v.w)));
        unsigned nh = rne_bf16(n);
        unsigned nl = rne_bf16(n - bf16_dec(nh));
        unsigned npk = nh | (nl << 16);
        float w0 = -2.0f * v.x, w1 = -2.0f * v.y, w2 = -2.0f * v.z, w3 = -v.w;
        unsigned h0 = rne_bf16(w0), h1 = rne_bf16(w1), h2 = rne_bf16(w2), h3 = rne_bf16(w3);
        unsigned l0 = rne_bf16(w0 - bf16_dec(h0)), l1 = rne_bf16(w1 - bf16_dec(h1));
        unsigned l2 = rne_bf16(w2 - bf16_dec(h2)), l3 = rne_bf16(w3 - bf16_dec(h3));
        wpred[i * 2 + 0] = make_uint4(h0 | (h1 << 16), h2 | (h3 << 16),
                                      l0 | (l1 << 16), l2 | (l3 << 16));   // [ah, al]
        wpred[i * 2 + 1] = make_uint4(h0 | (h1 << 16), h2 | (h3 << 16),
                                      onepk, npk);                          // [ah, 1,1, Pnh,Pnl]
    }
    {   // plain tgt record (col side)
        float4 v = tgt[i];
        float n = fmaf(v.x, v.x, fmaf(v.y, v.y, fmaf(v.z, v.z, 0.5f * v.w * v.w)));
        unsigned nh = rne_bf16(n);
        unsigned nl = rne_bf16(n - bf16_dec(nh));
        unsigned npk = nh | (nl << 16);
        unsigned g0 = rne_bf16(v.x), g1 = rne_bf16(v.y), g2 = rne_bf16(v.z), g3 = rne_bf16(v.w);
        unsigned m0 = rne_bf16(v.x - bf16_dec(g0)), m1 = rne_bf16(v.y - bf16_dec(g1));
        unsigned m2 = rne_bf16(v.z - bf16_dec(g2)), m3 = rne_bf16(v.w - bf16_dec(g3));
        ptgt[i * 2 + 0] = make_uint4(g0 | (g1 << 16), g2 | (g3 << 16),
                                     g0 | (g1 << 16), g2 | (g3 << 16));     // [bh, bh]
        ptgt[i * 2 + 1] = make_uint4(m0 | (m1 << 16), m2 | (m3 << 16),
                                     npk, onepk);                           // [bl, Tnh,Tnl, 1,1]
    }
}

__global__ __launch_bounds__(256, 4) void chamfer_mfma_kernel(
    const bf16x8* __restrict__ wpred, const bf16x8* __restrict__ ptgt,
    unsigned int* __restrict__ minbuf)
{
    const int lane = threadIdx.x & 63;
    const int wave = threadIdx.x >> 6;
    const int half = lane >> 5;     // selects k0-7 vs k8-15 record
    const int lid  = lane & 31;

    const int rowBase = blockIdx.x * RPB + wave * 64;
    const int colBase = blockIdx.y * CPB;

    bf16x8 a0 = wpred[(rowBase +      lid) * 2 + half];
    bf16x8 a1 = wpred[(rowBase + 32 + lid) * 2 + half];

    float mr0[16], mr1[16], mc[16];
#pragma unroll
    for (int r = 0; r < 16; ++r) { mr0[r] = 3.0e38f; mr1[r] = 3.0e38f; mc[r] = 3.0e38f; }

    const bf16x8* bp = ptgt + (colBase + lid) * 2 + half;
    const f32x16 kZero = (f32x16)(0.0f);

    // full unroll so mc[] stays in registers (compile-time indices)
#pragma unroll
    for (int tp = 0; tp < CPB / 64; ++tp) {
        bf16x8 b0 = bp[(2 * tp) * 64];
        bf16x8 b1 = bp[(2 * tp + 1) * 64];
        // row-tile 0 (rows 0-31), both col-tiles
        f32x16 accA0 = __builtin_amdgcn_mfma_f32_32x32x16_bf16(a0, b0, kZero, 0, 0, 0);
        f32x16 accA1 = __builtin_amdgcn_mfma_f32_32x32x16_bf16(a0, b1, kZero, 0, 0, 0);
#pragma unroll
        for (int r = 0; r < 16; ++r)
            mr0[r] = fminf(fminf(accA0[r], accA1[r]), mr0[r]);   // v_min3
#pragma unroll
        for (int q = 0; q < 8; ++q) {
            mc[2 * tp]     = fminf(fminf(accA0[2 * q], accA0[2 * q + 1]), mc[2 * tp]);
            mc[2 * tp + 1] = fminf(fminf(accA1[2 * q], accA1[2 * q + 1]), mc[2 * tp + 1]);
        }
        // row-tile 1 (rows 32-63)
        f32x16 accB0 = __builtin_amdgcn_mfma_f32_32x32x16_bf16(a1, b0, kZero, 0, 0, 0);
        f32x16 accB1 = __builtin_amdgcn_mfma_f32_32x32x16_bf16(a1, b1, kZero, 0, 0, 0);
#pragma unroll
        for (int r = 0; r < 16; ++r)
            mr1[r] = fminf(fminf(accB0[r], accB1[r]), mr1[r]);
#pragma unroll
        for (int q = 0; q < 8; ++q) {
            mc[2 * tp]     = fminf(fminf(accB0[2 * q], accB0[2 * q + 1]), mc[2 * tp]);
            mc[2 * tp + 1] = fminf(fminf(accB1[2 * q], accB1[2 * q + 1]), mc[2 * tp + 1]);
        }
    }

    __shared__ float red[RPB];             // per-block row mins
    __shared__ float colred[4][16][32];    // per-wave col partials (8 KB)

    // row mins: cross-lane min over the 32 col-lanes
    // C/D layout: col=lane&31, row=(reg&3)+8*(reg>>2)+4*(lane>>5)
#pragma unroll
    for (int r = 0; r < 16; ++r) {
        float v0 = mr0[r], v1 = mr1[r];
        v0 = fminf(v0, __shfl_xor(v0, 16)); v1 = fminf(v1, __shfl_xor(v1, 16));
        v0 = fminf(v0, __shfl_xor(v0, 8));  v1 = fminf(v1, __shfl_xor(v1, 8));
        v0 = fminf(v0, __shfl_xor(v0, 4));  v1 = fminf(v1, __shfl_xor(v1, 4));
        v0 = fminf(v0, __shfl_xor(v0, 2));  v1 = fminf(v1, __shfl_xor(v1, 2));
        v0 = fminf(v0, __shfl_xor(v0, 1));  v1 = fminf(v1, __shfl_xor(v1, 1));
        if (lid == 0) {
            int row = (r & 3) + 8 * (r >> 2) + 4 * half;
            red[wave * 64 + row]      = v0;
            red[wave * 64 + 32 + row] = v1;
        }
    }
    // col mins: merge the two lane-halves (same col), stage per-wave partials
#pragma unroll
    for (int t = 0; t < 16; ++t) {
        float v = fminf(mc[t], __shfl_xor(mc[t], 32));
        if (half == 0) colred[wave][t][lid] = v;
    }
    __syncthreads();

    {   // one row per thread
        float v = fmaxf(red[threadIdx.x], 0.0f);
        atomicMin(&minbuf[blockIdx.x * RPB + threadIdx.x], __float_as_uint(v));
    }
#pragma unroll
    for (int s = 0; s < 2; ++s) {   // two cols per thread
        int c = threadIdx.x + s * 256;
        int t = c >> 5, l = c & 31;
        float v = fminf(fminf(colred[0][t][l], colred[1][t][l]),
                        fminf(colred[2][t][l], colred[3][t][l]));
        v = fmaxf(v, 0.0f);
        atomicMin(&minbuf[NPTS + colBase + c], __float_as_uint(v));
    }
}

__global__ __launch_bounds__(1024) void chamfer_reduce_kernel(
    const unsigned int* __restrict__ minbuf, float* __restrict__ out)
{
    __shared__ float red[16];
    const uint4* mb4 = (const uint4*)minbuf;
    float s = 0.0f;
#pragma unroll
    for (int it = 0; it < (2 * NPTS / 4) / 1024; ++it) {
        uint4 u = mb4[it * 1024 + threadIdx.x];
        s += __uint_as_float(u.x) + __uint_as_float(u.y)
           + __uint_as_float(u.z) + __uint_as_float(u.w);
    }
#pragma unroll
    for (int off = 32; off > 0; off >>= 1)
        s += __shfl_down(s, off);
    const int wave = threadIdx.x >> 6;
    const int lane = threadIdx.x & 63;
    if (lane == 0) red[wave] = s;
    __syncthreads();
    if (threadIdx.x == 0) {
        float t = 0.0f;
#pragma unroll
        for (int w = 0; w < 16; ++w) t += red[w];
        out[0] = t * (1.0f / (float)NPTS);
    }
}

extern "C" void kernel_launch(void* const* d_in, const int* in_sizes, int n_in,
                              void* d_out, int out_size, void* d_ws, size_t ws_size,
                              hipStream_t stream) {
    const float4* pred = (const float4*)d_in[0];
    const float4* tgt  = (const float4*)d_in[1];

    unsigned int* minbuf = (unsigned int*)d_ws;                 // 128 KB
    uint4* wpred = (uint4*)((char*)d_ws + 2 * NPTS * 4);        // 512 KB
    uint4* ptgt  = wpred + 2 * NPTS;                            // 512 KB

    prep_kernel<<<NPTS / 256, 256, 0, stream>>>(pred, tgt, wpred, ptgt, minbuf);

    dim3 grid(NRB, NCB);   // (64, 32) = 2048 blocks, single pass over M
    chamfer_mfma_kernel<<<grid, 256, 0, stream>>>(
        (const bf16x8*)wpred, (const bf16x8*)ptgt, minbuf);

    chamfer_reduce_kernel<<<1, 1024, 0, stream>>>(minbuf, (float*)d_out);
}

// Round 8
// 1705.770 us; speedup vs baseline: 1.3449x; 1.3449x over previous
//
#include <hip/hip_runtime.h>

#define NPTS   16384
#define RPB    256      // rows per block (4 waves x 64)
#define CPB    512      // cols per block
#define NRB    (NPTS / RPB)   // 64
#define NCB    (NPTS / CPB)   // 32

typedef short  bf16x8 __attribute__((ext_vector_type(8)));
typedef float  f32x16 __attribute__((ext_vector_type(16)));

// ---- bf16 split helpers (RNE) ----
__device__ __forceinline__ unsigned rne_bf16(float f) {
    unsigned u = __float_as_uint(f);
    return (u + 0x7fffu + ((u >> 16) & 1u)) >> 16;
}
__device__ __forceinline__ float bf16_dec(unsigned h) {
    return __uint_as_float(h << 16);
}
#define ONE_BF 0x3f80u

// K=16 slot map (A = weighted pred, B = plain tgt):
//  k0-3: ah*bh  k4-7: al*bh  k8-11: ah*bl  k12-13: 1*Tnh,1*Tnl  k14-15: Pnh*1,Pnl*1
// => acc = hi-precision dot + Tn_j + Pn_i = combined(i,j) directly.
// combined() is symmetric in (pred,tgt): row-mins of M = min_p2g,
// col-mins of M = min_g2p. ONE pass serves both directions.
// Record layout per point: 2 x bf16x8 (lane<32 reads rec[0], lane>=32 rec[1]).

__global__ __launch_bounds__(256) void prep_kernel(
    const float4* __restrict__ pred, const float4* __restrict__ tgt,
    uint4* __restrict__ wpred, uint4* __restrict__ ptgt,
    unsigned int* __restrict__ minbuf)
{
    int i = blockIdx.x * 256 + threadIdx.x;
    if (i >= NPTS) return;

    minbuf[i]        = 0x7f7f7f7fu;   // 3.39e38f
    minbuf[i + NPTS] = 0x7f7f7f7fu;

    unsigned onepk = ONE_BF | (ONE_BF << 16);

    {   // weighted pred record (row side)
        float4 v = pred[i];
        float n = fmaf(v.x, v.x, fmaf(v.y, v.y, fmaf(v.z, v.z, 0.5f * v.w * v.w)));
        unsigned nh = rne_bf16(n);
        unsigned nl = rne_bf16(n - bf16_dec(nh));
        unsigned npk = nh | (nl << 16);
        float w0 = -2.0f * v.x, w1 = -2.0f * v.y, w2 = -2.0f * v.z, w3 = -v.w;
        unsigned h0 = rne_bf16(w0), h1 = rne_bf16(w1), h2 = rne_bf16(w2), h3 = rne_bf16(w3);
        unsigned l0 = rne_bf16(w0 - bf16_dec(h0)), l1 = rne_bf16(w1 - bf16_dec(h1));
        unsigned l2 = rne_bf16(w2 - bf16_dec(h2)), l3 = rne_bf16(w3 - bf16_dec(h3));
        wpred[i * 2 + 0] = make_uint4(h0 | (h1 << 16), h2 | (h3 << 16),
                                      l0 | (l1 << 16), l2 | (l3 << 16));   // [ah, al]
        wpred[i * 2 + 1] = make_uint4(h0 | (h1 << 16), h2 | (h3 << 16),
                                      onepk, npk);                          // [ah, 1,1, Pnh,Pnl]
    }
    {   // plain tgt record (col side)
        float4 v = tgt[i];
        float n = fmaf(v.x, v.x, fmaf(v.y, v.y, fmaf(v.z, v.z, 0.5f * v.w * v.w)));
        unsigned nh = rne_bf16(n);
        unsigned nl = rne_bf16(n - bf16_dec(nh));
        unsigned npk = nh | (nl << 16);
        unsigned g0 = rne_bf16(v.x), g1 = rne_bf16(v.y), g2 = rne_bf16(v.z), g3 = rne_bf16(v.w);
        unsigned m0 = rne_bf16(v.x - bf16_dec(g0)), m1 = rne_bf16(v.y - bf16_dec(g1));
        unsigned m2 = rne_bf16(v.z - bf16_dec(g2)), m3 = rne_bf16(v.w - bf16_dec(g3));
        ptgt[i * 2 + 0] = make_uint4(g0 | (g1 << 16), g2 | (g3 << 16),
                                     g0 | (g1 << 16), g2 | (g3 << 16));     // [bh, bh]
        ptgt[i * 2 + 1] = make_uint4(m0 | (m1 << 16), m2 | (m3 << 16),
                                     npk, onepk);                           // [bl, Tnh,Tnl, 1,1]
    }
}

// NOTE: __launch_bounds__(256,2) -> 256-VGPR budget. R7 used (256,4) (128 cap),
// the tp-loop didn't unroll, mc[] became runtime-indexed -> scratch -> 7.8 GB
// of spill traffic per dispatch (rule #20). STEP() macro makes every mc index
// a literal so codegen cannot regress to scratch even if scheduling changes.
__global__ __launch_bounds__(256, 2) void chamfer_mfma_kernel(
    const bf16x8* __restrict__ wpred, const bf16x8* __restrict__ ptgt,
    unsigned int* __restrict__ minbuf)
{
    const int lane = threadIdx.x & 63;
    const int wave = threadIdx.x >> 6;
    const int half = lane >> 5;     // selects k0-7 vs k8-15 record
    const int lid  = lane & 31;

    const int rowBase = blockIdx.x * RPB + wave * 64;
    const int colBase = blockIdx.y * CPB;

    bf16x8 a0 = wpred[(rowBase +      lid) * 2 + half];
    bf16x8 a1 = wpred[(rowBase + 32 + lid) * 2 + half];

    float mr0[16], mr1[16], mc[16];
#pragma unroll
    for (int r = 0; r < 16; ++r) { mr0[r] = 3.0e38f; mr1[r] = 3.0e38f; mc[r] = 3.0e38f; }

    const bf16x8* bp = ptgt + (colBase + lid) * 2 + half;
    const f32x16 kZero = (f32x16)(0.0f);

#define STEP(TP)                                                                  \
    {                                                                             \
        bf16x8 b0 = bp[(2 * (TP)) * 64];                                          \
        bf16x8 b1 = bp[(2 * (TP) + 1) * 64];                                      \
        f32x16 acc0 = __builtin_amdgcn_mfma_f32_32x32x16_bf16(a0, b0, kZero, 0, 0, 0); \
        f32x16 acc1 = __builtin_amdgcn_mfma_f32_32x32x16_bf16(a0, b1, kZero, 0, 0, 0); \
        _Pragma("unroll")                                                         \
        for (int r = 0; r < 16; ++r)                                              \
            mr0[r] = fminf(fminf(acc0[r], acc1[r]), mr0[r]);                      \
        _Pragma("unroll")                                                         \
        for (int q = 0; q < 8; ++q) {                                             \
            mc[2 * (TP)]     = fminf(fminf(acc0[2 * q], acc0[2 * q + 1]), mc[2 * (TP)]);     \
            mc[2 * (TP) + 1] = fminf(fminf(acc1[2 * q], acc1[2 * q + 1]), mc[2 * (TP) + 1]); \
        }                                                                         \
        acc0 = __builtin_amdgcn_mfma_f32_32x32x16_bf16(a1, b0, kZero, 0, 0, 0);   \
        acc1 = __builtin_amdgcn_mfma_f32_32x32x16_bf16(a1, b1, kZero, 0, 0, 0);   \
        _Pragma("unroll")                                                         \
        for (int r = 0; r < 16; ++r)                                              \
            mr1[r] = fminf(fminf(acc0[r], acc1[r]), mr1[r]);                      \
        _Pragma("unroll")                                                         \
        for (int q = 0; q < 8; ++q) {                                             \
            mc[2 * (TP)]     = fminf(fminf(acc0[2 * q], acc0[2 * q + 1]), mc[2 * (TP)]);     \
            mc[2 * (TP) + 1] = fminf(fminf(acc1[2 * q], acc1[2 * q + 1]), mc[2 * (TP) + 1]); \
        }                                                                         \
    }

    STEP(0) STEP(1) STEP(2) STEP(3) STEP(4) STEP(5) STEP(6) STEP(7)
#undef STEP

    __shared__ float red[RPB];             // per-block row mins
    __shared__ float colred[4][16][32];    // per-wave col partials (8 KB)

    // row mins: cross-lane min over the 32 col-lanes
    // C/D layout: col=lane&31, row=(reg&3)+8*(reg>>2)+4*(lane>>5)
#pragma unroll
    for (int r = 0; r < 16; ++r) {
        float v0 = mr0[r], v1 = mr1[r];
        v0 = fminf(v0, __shfl_xor(v0, 16)); v1 = fminf(v1, __shfl_xor(v1, 16));
        v0 = fminf(v0, __shfl_xor(v0, 8));  v1 = fminf(v1, __shfl_xor(v1, 8));
        v0 = fminf(v0, __shfl_xor(v0, 4));  v1 = fminf(v1, __shfl_xor(v1, 4));
        v0 = fminf(v0, __shfl_xor(v0, 2));  v1 = fminf(v1, __shfl_xor(v1, 2));
        v0 = fminf(v0, __shfl_xor(v0, 1));  v1 = fminf(v1, __shfl_xor(v1, 1));
        if (lid == 0) {
            int row = (r & 3) + 8 * (r >> 2) + 4 * half;
            red[wave * 64 + row]      = v0;
            red[wave * 64 + 32 + row] = v1;
        }
    }
    // col mins: merge the two lane-halves (same col), stage per-wave partials
#pragma unroll
    for (int t = 0; t < 16; ++t) {
        float v = fminf(mc[t], __shfl_xor(mc[t], 32));
        if (half == 0) colred[wave][t][lid] = v;
    }
    __syncthreads();

    {   // one row per thread
        float v = fmaxf(red[threadIdx.x], 0.0f);
        atomicMin(&minbuf[blockIdx.x * RPB + threadIdx.x], __float_as_uint(v));
    }
#pragma unroll
    for (int s = 0; s < 2; ++s) {   // two cols per thread
        int c = threadIdx.x + s * 256;
        int t = c >> 5, l = c & 31;
        float v = fminf(fminf(colred[0][t][l], colred[1][t][l]),
                        fminf(colred[2][t][l], colred[3][t][l]));
        v = fmaxf(v, 0.0f);
        atomicMin(&minbuf[NPTS + colBase + c], __float_as_uint(v));
    }
}

__global__ __launch_bounds__(1024) void chamfer_reduce_kernel(
    const unsigned int* __restrict__ minbuf, float* __restrict__ out)
{
    __shared__ float red[16];
    const uint4* mb4 = (const uint4*)minbuf;
    float s = 0.0f;
#pragma unroll
    for (int it = 0; it < (2 * NPTS / 4) / 1024; ++it) {
        uint4 u = mb4[it * 1024 + threadIdx.x];
        s += __uint_as_float(u.x) + __uint_as_float(u.y)
           + __uint_as_float(u.z) + __uint_as_float(u.w);
    }
#pragma unroll
    for (int off = 32; off > 0; off >>= 1)
        s += __shfl_down(s, off);
    const int wave = threadIdx.x >> 6;
    const int lane = threadIdx.x & 63;
    if (lane == 0) red[wave] = s;
    __syncthreads();
    if (threadIdx.x == 0) {
        float t = 0.0f;
#pragma unroll
        for (int w = 0; w < 16; ++w) t += red[w];
        out[0] = t * (1.0f / (float)NPTS);
    }
}

extern "C" void kernel_launch(void* const* d_in, const int* in_sizes, int n_in,
                              void* d_out, int out_size, void* d_ws, size_t ws_size,
                              hipStream_t stream) {
    const float4* pred = (const float4*)d_in[0];
    const float4* tgt  = (const float4*)d_in[1];

    unsigned int* minbuf = (unsigned int*)d_ws;                 // 128 KB
    uint4* wpred = (uint4*)((char*)d_ws + 2 * NPTS * 4);        // 512 KB
    uint4* ptgt  = wpred + 2 * NPTS;                            // 512 KB

    prep_kernel<<<NPTS / 256, 256, 0, stream>>>(pred, tgt, wpred, ptgt, minbuf);

    dim3 grid(NRB, NCB);   // (64, 32) = 2048 blocks, single pass over M
    chamfer_mfma_kernel<<<grid, 256, 0, stream>>>(
        (const bf16x8*)wpred, (const bf16x8*)ptgt, minbuf);

    chamfer_reduce_kernel<<<1, 1024, 0, stream>>>(minbuf, (float*)d_out);
}

// Round 9
// 1584.131 us; speedup vs baseline: 1.4482x; 1.0768x over previous
//
#include <hip/hip_runtime.h>

#define NPTS   16384
#define RPB    256      // rows per block (4 waves x 64)
#define CPB    512      // cols per block
#define NRB    (NPTS / RPB)   // 64
#define NCB    (NPTS / CPB)   // 32

typedef short  bf16x8 __attribute__((ext_vector_type(8)));
typedef float  f32x16 __attribute__((ext_vector_type(16)));

// ---- bf16 split helpers (RNE) ----
__device__ __forceinline__ unsigned rne_bf16(float f) {
    unsigned u = __float_as_uint(f);
    return (u + 0x7fffu + ((u >> 16) & 1u)) >> 16;
}
__device__ __forceinline__ float bf16_dec(unsigned h) {
    return __uint_as_float(h << 16);
}
#define ONE_BF 0x3f80u

// K=16 slot map (A = weighted pred, B = plain tgt):
//  k0-3: ah*bh  k4-7: al*bh  k8-11: ah*bl  k12-13: 1*Tnh,1*Tnl  k14-15: Pnh*1,Pnl*1
// => acc = hi-precision dot + Tn_j + Pn_i = combined(i,j) directly.
// combined() is symmetric in (pred,tgt): row-mins of M = min_p2g,
// col-mins of M = min_g2p. ONE pass serves both directions.
// Record layout per point: 2 x bf16x8 (lane<32 reads rec[0], lane>=32 rec[1]).

__global__ __launch_bounds__(256) void prep_kernel(
    const float4* __restrict__ pred, const float4* __restrict__ tgt,
    uint4* __restrict__ wpred, uint4* __restrict__ ptgt,
    unsigned int* __restrict__ minbuf)
{
    int i = blockIdx.x * 256 + threadIdx.x;
    if (i >= NPTS) return;

    minbuf[i]        = 0x7f7f7f7fu;   // 3.39e38f
    minbuf[i + NPTS] = 0x7f7f7f7fu;

    unsigned onepk = ONE_BF | (ONE_BF << 16);

    {   // weighted pred record (row side)
        float4 v = pred[i];
        float n = fmaf(v.x, v.x, fmaf(v.y, v.y, fmaf(v.z, v.z, 0.5f * v.w * v.w)));
        unsigned nh = rne_bf16(n);
        unsigned nl = rne_bf16(n - bf16_dec(nh));
        unsigned npk = nh | (nl << 16);
        float w0 = -2.0f * v.x, w1 = -2.0f * v.y, w2 = -2.0f * v.z, w3 = -v.w;
        unsigned h0 = rne_bf16(w0), h1 = rne_bf16(w1), h2 = rne_bf16(w2), h3 = rne_bf16(w3);
        unsigned l0 = rne_bf16(w0 - bf16_dec(h0)), l1 = rne_bf16(w1 - bf16_dec(h1));
        unsigned l2 = rne_bf16(w2 - bf16_dec(h2)), l3 = rne_bf16(w3 - bf16_dec(h3));
        wpred[i * 2 + 0] = make_uint4(h0 | (h1 << 16), h2 | (h3 << 16),
                                      l0 | (l1 << 16), l2 | (l3 << 16));   // [ah, al]
        wpred[i * 2 + 1] = make_uint4(h0 | (h1 << 16), h2 | (h3 << 16),
                                      onepk, npk);                          // [ah, 1,1, Pnh,Pnl]
    }
    {   // plain tgt record (col side)
        float4 v = tgt[i];
        float n = fmaf(v.x, v.x, fmaf(v.y, v.y, fmaf(v.z, v.z, 0.5f * v.w * v.w)));
        unsigned nh = rne_bf16(n);
        unsigned nl = rne_bf16(n - bf16_dec(nh));
        unsigned npk = nh | (nl << 16);
        unsigned g0 = rne_bf16(v.x), g1 = rne_bf16(v.y), g2 = rne_bf16(v.z), g3 = rne_bf16(v.w);
        unsigned m0 = rne_bf16(v.x - bf16_dec(g0)), m1 = rne_bf16(v.y - bf16_dec(g1));
        unsigned m2 = rne_bf16(v.z - bf16_dec(g2)), m3 = rne_bf16(v.w - bf16_dec(g3));
        ptgt[i * 2 + 0] = make_uint4(g0 | (g1 << 16), g2 | (g3 << 16),
                                     g0 | (g1 << 16), g2 | (g3 << 16));     // [bh, bh]
        ptgt[i * 2 + 1] = make_uint4(m0 | (m1 << 16), m2 | (m3 << 16),
                                     npk, onepk);                           // [bl, Tnh,Tnl, 1,1]
    }
}

// R7/R8 spilled to scratch (5.8-7.8 GB FETCH/dispatch): the pre-RA scheduler
// hoists MFMAs across STEPs to hide latency, keeping many f32x16 accs live ->
// RA spills. Fix: sched_barrier(0x20) after each acc-pair consumption pins
// MFMA/VALU regions (only VMEM_READ may cross, so B-prefetch still hoists).
// Max live: mr0+mr1+mc (48) + one acc pair (32) + a/b frags (16) ~= 100 VGPR.
__global__ __launch_bounds__(256, 2) void chamfer_mfma_kernel(
    const bf16x8* __restrict__ wpred, const bf16x8* __restrict__ ptgt,
    unsigned int* __restrict__ minbuf)
{
    const int lane = threadIdx.x & 63;
    const int wave = threadIdx.x >> 6;
    const int half = lane >> 5;     // selects k0-7 vs k8-15 record
    const int lid  = lane & 31;

    const int rowBase = blockIdx.x * RPB + wave * 64;
    const int colBase = blockIdx.y * CPB;

    bf16x8 a0 = wpred[(rowBase +      lid) * 2 + half];
    bf16x8 a1 = wpred[(rowBase + 32 + lid) * 2 + half];

    float mr0[16], mr1[16], mc[16];
#pragma unroll
    for (int r = 0; r < 16; ++r) { mr0[r] = 3.0e38f; mr1[r] = 3.0e38f; mc[r] = 3.0e38f; }

    const bf16x8* bp = ptgt + (colBase + lid) * 2 + half;
    const f32x16 kZero = (f32x16)(0.0f);

#define HALFSTEP(AFRAG, MR, TP, B0, B1)                                           \
    {                                                                             \
        f32x16 acc0 = __builtin_amdgcn_mfma_f32_32x32x16_bf16(AFRAG, B0, kZero, 0, 0, 0); \
        f32x16 acc1 = __builtin_amdgcn_mfma_f32_32x32x16_bf16(AFRAG, B1, kZero, 0, 0, 0); \
        _Pragma("unroll")                                                         \
        for (int r = 0; r < 16; ++r)                                              \
            MR[r] = fminf(fminf(acc0[r], acc1[r]), MR[r]);                        \
        _Pragma("unroll")                                                         \
        for (int q = 0; q < 8; ++q) {                                             \
            mc[2 * (TP)]     = fminf(fminf(acc0[2 * q], acc0[2 * q + 1]), mc[2 * (TP)]);     \
            mc[2 * (TP) + 1] = fminf(fminf(acc1[2 * q], acc1[2 * q + 1]), mc[2 * (TP) + 1]); \
        }                                                                         \
        __builtin_amdgcn_sched_barrier(0x20); /* only VMEM_READ may cross */      \
    }

#define STEP(TP)                                                                  \
    {                                                                             \
        bf16x8 b0 = bp[(2 * (TP)) * 64];                                          \
        bf16x8 b1 = bp[(2 * (TP) + 1) * 64];                                      \
        HALFSTEP(a0, mr0, TP, b0, b1)                                             \
        HALFSTEP(a1, mr1, TP, b0, b1)                                             \
    }

    STEP(0) STEP(1) STEP(2) STEP(3) STEP(4) STEP(5) STEP(6) STEP(7)
#undef STEP
#undef HALFSTEP

    __shared__ float red[RPB];             // per-block row mins
    __shared__ float colred[4][16][32];    // per-wave col partials (8 KB)

    // row mins: cross-lane min over the 32 col-lanes
    // C/D layout: col=lane&31, row=(reg&3)+8*(reg>>2)+4*(lane>>5)
#pragma unroll
    for (int r = 0; r < 16; ++r) {
        float v0 = mr0[r], v1 = mr1[r];
        v0 = fminf(v0, __shfl_xor(v0, 16)); v1 = fminf(v1, __shfl_xor(v1, 16));
        v0 = fminf(v0, __shfl_xor(v0, 8));  v1 = fminf(v1, __shfl_xor(v1, 8));
        v0 = fminf(v0, __shfl_xor(v0, 4));  v1 = fminf(v1, __shfl_xor(v1, 4));
        v0 = fminf(v0, __shfl_xor(v0, 2));  v1 = fminf(v1, __shfl_xor(v1, 2));
        v0 = fminf(v0, __shfl_xor(v0, 1));  v1 = fminf(v1, __shfl_xor(v1, 1));
        if (lid == 0) {
            int row = (r & 3) + 8 * (r >> 2) + 4 * half;
            red[wave * 64 + row]      = v0;
            red[wave * 64 + 32 + row] = v1;
        }
    }
    // col mins: merge the two lane-halves (same col), stage per-wave partials
#pragma unroll
    for (int t = 0; t < 16; ++t) {
        float v = fminf(mc[t], __shfl_xor(mc[t], 32));
        if (half == 0) colred[wave][t][lid] = v;
    }
    __syncthreads();

    {   // one row per thread
        float v = fmaxf(red[threadIdx.x], 0.0f);
        atomicMin(&minbuf[blockIdx.x * RPB + threadIdx.x], __float_as_uint(v));
    }
#pragma unroll
    for (int s = 0; s < 2; ++s) {   // two cols per thread
        int c = threadIdx.x + s * 256;
        int t = c >> 5, l = c & 31;
        float v = fminf(fminf(colred[0][t][l], colred[1][t][l]),
                        fminf(colred[2][t][l], colred[3][t][l]));
        v = fmaxf(v, 0.0f);
        atomicMin(&minbuf[NPTS + colBase + c], __float_as_uint(v));
    }
}

__global__ __launch_bounds__(1024) void chamfer_reduce_kernel(
    const unsigned int* __restrict__ minbuf, float* __restrict__ out)
{
    __shared__ float red[16];
    const uint4* mb4 = (const uint4*)minbuf;
    float s = 0.0f;
#pragma unroll
    for (int it = 0; it < (2 * NPTS / 4) / 1024; ++it) {
        uint4 u = mb4[it * 1024 + threadIdx.x];
        s += __uint_as_float(u.x) + __uint_as_float(u.y)
           + __uint_as_float(u.z) + __uint_as_float(u.w);
    }
#pragma unroll
    for (int off = 32; off > 0; off >>= 1)
        s += __shfl_down(s, off);
    const int wave = threadIdx.x >> 6;
    const int lane = threadIdx.x & 63;
    if (lane == 0) red[wave] = s;
    __syncthreads();
    if (threadIdx.x == 0) {
        float t = 0.0f;
#pragma unroll
        for (int w = 0; w < 16; ++w) t += red[w];
        out[0] = t * (1.0f / (float)NPTS);
    }
}

extern "C" void kernel_launch(void* const* d_in, const int* in_sizes, int n_in,
                              void* d_out, int out_size, void* d_ws, size_t ws_size,
                              hipStream_t stream) {
    const float4* pred = (const float4*)d_in[0];
    const float4* tgt  = (const float4*)d_in[1];

    unsigned int* minbuf = (unsigned int*)d_ws;                 // 128 KB
    uint4* wpred = (uint4*)((char*)d_ws + 2 * NPTS * 4);        // 512 KB
    uint4* ptgt  = wpred + 2 * NPTS;                            // 512 KB

    prep_kernel<<<NPTS / 256, 256, 0, stream>>>(pred, tgt, wpred, ptgt, minbuf);

    dim3 grid(NRB, NCB);   // (64, 32) = 2048 blocks, single pass over M
    chamfer_mfma_kernel<<<grid, 256, 0, stream>>>(
        (const bf16x8*)wpred, (const bf16x8*)ptgt, minbuf);

    chamfer_reduce_kernel<<<1, 1024, 0, stream>>>(minbuf, (float*)d_out);
}